// Round 1
// baseline (4122.625 us; speedup 1.0000x reference)
//
#include <hip/hip_runtime.h>
#include <cmath>

#define NN 128
#define TT 20
#define ERNN 256
#define EPB 16
#define SPB 1016      /* spatial blocks: 16256/16 */
#define TOTB 1024     /* + 8 temporal blocks */
#define TEMPSC 15.875f /* (N-1)/sqrt(ATT) = 127/8 */

__device__ __forceinline__ float sigm(float x){ return 1.f/(1.f+__expf(-x)); }

__global__ void k_transpose(const float* __restrict__ s, float* __restrict__ d, int R, int C){
    int i = blockIdx.x*256 + threadIdx.x;
    if (i < R*C){ int r = i / C, c = i - r*C; d[c*R + r] = s[i]; }
}

__global__ void k_bias_sum(const float* __restrict__ a, const float* __restrict__ b,
                           float* __restrict__ o, int n){
    int i = blockIdx.x*256 + threadIdx.x;
    if (i < n) o[i] = a[i] + b[i];
}

// Edge LSTM: blocks [0,1016) spatial edges, [1016,1024) temporal (diagonal) edges.
// Each block owns EPB=16 edge rows; reads & writes only its own h_e/c_e rows -> race-free in-place.
// Thread q in [0,256) computes gate channels (q, q+256, q+512, q+768) for all 16 edges.
__global__ __launch_bounds__(256) void k_edge_lstm(
    const float* __restrict__ edges_t,           // [16384,2]
    float* __restrict__ h_e, float* __restrict__ c_e,  // [16384,256]
    const float* __restrict__ s_enc_w, const float* __restrict__ s_enc_b,
    const float* __restrict__ s_wcat,  const float* __restrict__ s_bsum,   // [320][1024], [1024]
    const float* __restrict__ t_enc_w, const float* __restrict__ t_enc_b,
    const float* __restrict__ t_wcat,  const float* __restrict__ t_bsum)
{
    __shared__ float xh[320][EPB];   // k-major: rows 0..63 = encoded x, 64..319 = h
    __shared__ int rows[EPB];
    const int bid = blockIdx.x, tid = threadIdx.x;
    const bool sp = (bid < SPB);
    const float* enc_w = sp ? s_enc_w : t_enc_w;
    const float* enc_b = sp ? s_enc_b : t_enc_b;
    const float* wcat  = sp ? s_wcat  : t_wcat;
    const float* bsum  = sp ? s_bsum  : t_bsum;

    if (tid < EPB) {
        int row;
        if (sp) {
            int se = bid*EPB + tid;           // < 16256
            int i = se / 127, jj = se - i*127;
            int j = jj + (jj >= i ? 1 : 0);   // ascending j skipping i (matches _OFFJ)
            row = i*NN + j;
        } else {
            int te = (bid - SPB)*EPB + tid;   // < 128
            row = te*NN + te;                 // diagonal
        }
        rows[tid] = row;
    }
    __syncthreads();

    // encoder: x[e][m] = relu(W e + b), E_IN=2
    for (int idx = tid; idx < EPB*64; idx += 256) {
        int el = idx >> 6, m = idx & 63;
        int row = rows[el];
        float e0 = edges_t[row*2], e1 = edges_t[row*2+1];
        xh[m][el] = fmaxf(fmaf(enc_w[m*2], e0, fmaf(enc_w[m*2+1], e1, enc_b[m])), 0.f);
    }
    // h tile (coalesced over k)
    for (int idx = tid; idx < EPB*ERNN; idx += 256) {
        int el = idx >> 8, k = idx & 255;
        xh[64+k][el] = h_e[rows[el]*ERNN + k];
    }
    __syncthreads();

    float ai[EPB], af[EPB], ag[EPB], ao[EPB];
    {
        float bi = bsum[tid], bf = bsum[tid+256], bg = bsum[tid+512], bo = bsum[tid+768];
        #pragma unroll
        for (int e = 0; e < EPB; ++e){ ai[e]=bi; af[e]=bf; ag[e]=bg; ao[e]=bo; }
    }
    for (int k = 0; k < 320; ++k) {
        const float* wr = wcat + k*1024;
        float wi = wr[tid], wf = wr[tid+256], wg = wr[tid+512], wo = wr[tid+768];
        const float4* xr = (const float4*)&xh[k][0];
        #pragma unroll
        for (int q = 0; q < 4; ++q) {
            float4 x4 = xr[q];
            float xs0 = x4.x, xs1 = x4.y, xs2 = x4.z, xs3 = x4.w;
            int e = q*4;
            ai[e+0]=fmaf(xs0,wi,ai[e+0]); af[e+0]=fmaf(xs0,wf,af[e+0]); ag[e+0]=fmaf(xs0,wg,ag[e+0]); ao[e+0]=fmaf(xs0,wo,ao[e+0]);
            ai[e+1]=fmaf(xs1,wi,ai[e+1]); af[e+1]=fmaf(xs1,wf,af[e+1]); ag[e+1]=fmaf(xs1,wg,ag[e+1]); ao[e+1]=fmaf(xs1,wo,ao[e+1]);
            ai[e+2]=fmaf(xs2,wi,ai[e+2]); af[e+2]=fmaf(xs2,wf,af[e+2]); ag[e+2]=fmaf(xs2,wg,ag[e+2]); ao[e+2]=fmaf(xs2,wo,ao[e+2]);
            ai[e+3]=fmaf(xs3,wi,ai[e+3]); af[e+3]=fmaf(xs3,wf,af[e+3]); ag[e+3]=fmaf(xs3,wg,ag[e+3]); ao[e+3]=fmaf(xs3,wo,ao[e+3]);
        }
    }
    #pragma unroll
    for (int e = 0; e < EPB; ++e) {
        int row = rows[e];
        float co = c_e[row*ERNN + tid];
        float c2 = sigm(af[e])*co + sigm(ai[e])*tanhf(ag[e]);
        float h2 = sigm(ao[e])*tanhf(c2);
        c_e[row*ERNN + tid] = c2;
        h_e[row*ERNN + tid] = h2;
    }
}

// Per-node: attention (folded: u = att_s_w^T te; logit_k = u.hs_k + te.att_s_b) + node LSTM + output.
__global__ __launch_bounds__(256) void k_node(
    const float* __restrict__ nodes_t,   // [128,2]
    const float* __restrict__ h_e,       // [16384,256] updated this step
    float* __restrict__ h_n, float* __restrict__ c_n,  // [128,128]
    float* __restrict__ out_t,           // [128,5]
    const float* __restrict__ att_t_w, const float* __restrict__ att_t_b,
    const float* __restrict__ att_s_w, const float* __restrict__ att_s_b,
    const float* __restrict__ n_enc_w, const float* __restrict__ n_enc_b,
    const float* __restrict__ n_attn_w, const float* __restrict__ n_attn_b,
    const float* __restrict__ n_wT, const float* __restrict__ n_bsum,  // [256][512], [512]
    const float* __restrict__ out_w, const float* __restrict__ out_b)
{
    const int i = blockIdx.x, tid = threadIdx.x;
    __shared__ float ht[ERNN];
    __shared__ float te[64];
    __shared__ float u[ERNN];
    __shared__ float lg[128];
    __shared__ float cat[512];
    __shared__ float xc[128];
    __shared__ float hnl[128];
    __shared__ float gl[512];
    __shared__ float smax, ssum, c0s;

    ht[tid] = h_e[(i*NN + i)*ERNN + tid];
    __syncthreads();
    if (tid < 64) {                       // te = att_t_w @ h_t + b
        float s = att_t_b[tid];
        const float* wr = att_t_w + tid*ERNN;
        for (int k = 0; k < ERNN; ++k) s = fmaf(wr[k], ht[k], s);
        te[tid] = s;
    }
    __syncthreads();
    {                                     // u = att_s_w^T @ te
        float s = 0.f;
        for (int m = 0; m < 64; ++m) s = fmaf(att_s_w[m*ERNN + tid], te[m], s);
        u[tid] = s;
    }
    if (tid == 0) {                       // c0 = te . att_s_b
        float s = 0.f;
        for (int m = 0; m < 64; ++m) s = fmaf(te[m], att_s_b[m], s);
        c0s = s;
    }
    __syncthreads();
    {                                     // logits: 2 threads per slot (halves of d)
        int slot = tid >> 1, half = tid & 1;
        float part = 0.f;
        if (slot < 127) {
            int j = slot + (slot >= i ? 1 : 0);
            const float* hs = h_e + (i*NN + j)*ERNN + half*128;
            const float* uu = u + half*128;
            for (int d = 0; d < 128; ++d) part = fmaf(uu[d], hs[d], part);
        }
        part += __shfl_xor(part, 1);
        if (slot < 127 && (half == 0)) lg[slot] = (part + c0s) * TEMPSC;
        if (tid == 255) lg[127] = -1e30f;
    }
    __syncthreads();
    if (tid < 64) {
        float a = fmaxf(lg[tid], lg[tid+64]);
        for (int off = 32; off; off >>= 1) a = fmaxf(a, __shfl_xor(a, off));
        if (tid == 0) smax = a;
    }
    __syncthreads();
    if (tid < 128) lg[tid] = (tid < 127) ? __expf(lg[tid] - smax) : 0.f;
    __syncthreads();
    if (tid < 64) {
        float a = lg[tid] + lg[tid+64];
        for (int off = 32; off; off >>= 1) a += __shfl_xor(a, off);
        if (tid == 0) ssum = a;
    }
    __syncthreads();
    {                                     // weighted sum over spatial hiddens (coalesced in d)
        float acc = 0.f;
        for (int slot = 0; slot < 127; ++slot) {
            int j = slot + (slot >= i ? 1 : 0);
            acc = fmaf(lg[slot], h_e[(i*NN + j)*ERNN + tid], acc);
        }
        cat[tid] = ht[tid];
        cat[256 + tid] = acc / ssum;
    }
    if (tid < 128) hnl[tid] = h_n[i*128 + tid];
    __syncthreads();
    if (tid < 64) {                       // wave0: enc
        float p0 = nodes_t[i*2], p1 = nodes_t[i*2+1];
        xc[tid] = fmaxf(fmaf(n_enc_w[tid*2], p0, fmaf(n_enc_w[tid*2+1], p1, n_enc_b[tid])), 0.f);
    } else if (tid < 128) {               // wave1: h_emb
        int m = tid - 64;
        float s = n_attn_b[m];
        const float* wr = n_attn_w + m*512;
        for (int d = 0; d < 512; ++d) s = fmaf(wr[d], cat[d], s);
        xc[tid] = fmaxf(s, 0.f);
    }
    __syncthreads();
    #pragma unroll
    for (int rep = 0; rep < 2; ++rep) {   // node LSTM gates, K-major transposed weights
        int n = tid + rep*256;
        float s = n_bsum[n];
        for (int k = 0; k < 128; ++k) s = fmaf(n_wT[k*512 + n], xc[k], s);
        for (int k = 0; k < 128; ++k) s = fmaf(n_wT[(128+k)*512 + n], hnl[k], s);
        gl[n] = s;
    }
    __syncthreads();
    if (tid < 128) {
        float co = c_n[i*128 + tid];
        float c2 = sigm(gl[128+tid])*co + sigm(gl[tid])*tanhf(gl[256+tid]);
        float h2 = sigm(gl[384+tid])*tanhf(c2);
        c_n[i*128+tid] = c2;
        h_n[i*128+tid] = h2;
        hnl[tid] = h2;
    }
    __syncthreads();
    if (tid < 5) {
        float s = out_b[tid];
        const float* wr = out_w + tid*128;
        for (int k = 0; k < 128; ++k) s = fmaf(wr[k], hnl[k], s);
        out_t[i*5 + tid] = s;
    }
}

extern "C" void kernel_launch(void* const* d_in, const int* in_sizes, int n_in,
                              void* d_out, int out_size, void* d_ws, size_t ws_size,
                              hipStream_t stream)
{
    const float* nodes   = (const float*)d_in[0];
    const float* edges   = (const float*)d_in[1];
    const float* h_e0    = (const float*)d_in[2];
    const float* c_e0    = (const float*)d_in[3];
    const float* h_n0    = (const float*)d_in[4];
    const float* c_n0    = (const float*)d_in[5];
    const float* t_enc_w = (const float*)d_in[6];
    const float* t_enc_b = (const float*)d_in[7];
    const float* t_wih   = (const float*)d_in[8];
    const float* t_whh   = (const float*)d_in[9];
    const float* t_bih   = (const float*)d_in[10];
    const float* t_bhh   = (const float*)d_in[11];
    const float* s_enc_w = (const float*)d_in[12];
    const float* s_enc_b = (const float*)d_in[13];
    const float* s_wih   = (const float*)d_in[14];
    const float* s_whh   = (const float*)d_in[15];
    const float* s_bih   = (const float*)d_in[16];
    const float* s_bhh   = (const float*)d_in[17];
    const float* att_t_w = (const float*)d_in[18];
    const float* att_t_b = (const float*)d_in[19];
    const float* att_s_w = (const float*)d_in[20];
    const float* att_s_b = (const float*)d_in[21];
    const float* n_enc_w = (const float*)d_in[22];
    const float* n_enc_b = (const float*)d_in[23];
    const float* n_attn_w= (const float*)d_in[24];
    const float* n_attn_b= (const float*)d_in[25];
    const float* n_wih   = (const float*)d_in[26];
    const float* n_whh   = (const float*)d_in[27];
    const float* n_bih   = (const float*)d_in[28];
    const float* n_bhh   = (const float*)d_in[29];
    const float* out_w   = (const float*)d_in[30];
    const float* out_b   = (const float*)d_in[31];
    float* out = (float*)d_out;

    float* ws = (float*)d_ws;
    float* h_e    = ws;  ws += 16384*256;
    float* c_e    = ws;  ws += 16384*256;
    float* h_n    = ws;  ws += 128*128;
    float* c_n    = ws;  ws += 128*128;
    float* t_wcat = ws;  ws += 320*1024;
    float* t_bs   = ws;  ws += 1024;
    float* s_wcat = ws;  ws += 320*1024;
    float* s_bs   = ws;  ws += 1024;
    float* n_wT   = ws;  ws += 256*512;
    float* n_bs   = ws;  ws += 512;

    // re-init recurrent state every call (ws is not re-poisoned between replays)
    hipMemcpyAsync(h_e, h_e0, (size_t)16384*256*sizeof(float), hipMemcpyDeviceToDevice, stream);
    hipMemcpyAsync(c_e, c_e0, (size_t)16384*256*sizeof(float), hipMemcpyDeviceToDevice, stream);
    hipMemcpyAsync(h_n, h_n0, (size_t)128*128*sizeof(float), hipMemcpyDeviceToDevice, stream);
    hipMemcpyAsync(c_n, c_n0, (size_t)128*128*sizeof(float), hipMemcpyDeviceToDevice, stream);

    // K-major transposed weight prep (once per launch)
    auto TR = [&](const float* s, float* d, int R, int C){
        int n = R*C; k_transpose<<<(n+255)/256, 256, 0, stream>>>(s, d, R, C);
    };
    TR(t_wih, t_wcat,            1024, 64);
    TR(t_whh, t_wcat + 64*1024,  1024, 256);
    TR(s_wih, s_wcat,            1024, 64);
    TR(s_whh, s_wcat + 64*1024,  1024, 256);
    TR(n_wih, n_wT,              512, 128);
    TR(n_whh, n_wT + 128*512,    512, 128);
    k_bias_sum<<<4, 256, 0, stream>>>(t_bih, t_bhh, t_bs, 1024);
    k_bias_sum<<<4, 256, 0, stream>>>(s_bih, s_bhh, s_bs, 1024);
    k_bias_sum<<<2, 256, 0, stream>>>(n_bih, n_bhh, n_bs, 512);

    for (int t = 0; t < TT; ++t) {
        k_edge_lstm<<<TOTB, 256, 0, stream>>>(edges + (size_t)t*16384*2, h_e, c_e,
            s_enc_w, s_enc_b, s_wcat, s_bs, t_enc_w, t_enc_b, t_wcat, t_bs);
        k_node<<<NN, 256, 0, stream>>>(nodes + (size_t)t*NN*2, h_e, h_n, c_n,
            out + (size_t)t*NN*5,
            att_t_w, att_t_b, att_s_w, att_s_b, n_enc_w, n_enc_b,
            n_attn_w, n_attn_b, n_wT, n_bs, out_w, out_b);
    }
}

// Round 4
// 1960.130 us; speedup vs baseline: 2.1032x; 2.1032x over previous
//
#include <hip/hip_runtime.h>
#include <cmath>

#define NN 128
#define TT 20
#define ERNN 256
#define TEMPSC 15.875f /* (N-1)/sqrt(ATT) = 127/8 */

typedef __attribute__((ext_vector_type(8))) short bf16x8;
typedef __attribute__((ext_vector_type(4))) float f32x4;

__device__ __forceinline__ float sigm(float x){ return 1.f/(1.f+__expf(-x)); }
__device__ __forceinline__ float b2f(unsigned short u){ union{unsigned int i; float f;} v; v.i = ((unsigned int)u)<<16; return v.f; }
__device__ __forceinline__ unsigned short f2b(float x){ union{float f; unsigned int u;} v; v.f = x; unsigned int r = v.u + 0x7fffu + ((v.u>>16)&1u); return (unsigned short)(r>>16); }

typedef __attribute__((address_space(3))) unsigned int lds_u32;
typedef __attribute__((address_space(1))) unsigned int glb_u32;
__device__ __forceinline__ void glds16(const void* g, void* l){
    __builtin_amdgcn_global_load_lds((const glb_u32*)g, (lds_u32*)l, 16, 0, 0);
}

__global__ void k_transpose(const float* __restrict__ s, float* __restrict__ d, int R, int C){
    int i = blockIdx.x*256 + threadIdx.x;
    if (i < R*C){ int r = i / C, c = i - r*C; d[c*R + r] = s[i]; }
}

__global__ void k_bias_sum(const float* __restrict__ a, const float* __restrict__ b,
                           float* __restrict__ o, int n){
    int i = blockIdx.x*256 + threadIdx.x;
    if (i < n) o[i] = a[i] + b[i];
}

// wT[c][k] split hi/lo bf16; c gate-interleaved: ch=(c>>6)*16+(c&15), g=(c>>4)&3
__global__ void k_prep_w(const float* __restrict__ wih, const float* __restrict__ whh,
                         unsigned short* __restrict__ wHi, unsigned short* __restrict__ wLo){
    int idx = blockIdx.x*256 + threadIdx.x;
    if (idx >= 1024*320) return;
    int c = idx / 320, k = idx - c*320;
    int ch = ((c>>6)<<4) + (c&15), g = (c>>4)&3;
    int r = g*256 + ch;
    float v = (k < 64) ? wih[r*64 + k] : whh[r*256 + (k-64)];
    unsigned short hi = f2b(v);
    wHi[idx] = hi;
    wLo[idx] = f2b(v - b2f(hi));
}

__global__ void k_prep_b(const float* __restrict__ bih, const float* __restrict__ bhh,
                         float* __restrict__ bs){
    int c = blockIdx.x*256 + threadIdx.x;
    if (c < 1024){ int ch = ((c>>6)<<4)+(c&15), g=(c>>4)&3; int r = g*256+ch; bs[c] = bih[r] + bhh[r]; }
}

// gather (i,j)-layout initial state into se-order, split h into hi/lo
__global__ void k_init_state(const float* __restrict__ h0, const float* __restrict__ c0,
                             unsigned short* __restrict__ hHi, unsigned short* __restrict__ hLo,
                             float* __restrict__ c_all){
    int idx = blockIdx.x*256 + threadIdx.x;
    if (idx >= 16384*256) return;
    int r = idx >> 8, d = idx & 255;
    int row_ij;
    if (r < 16256){ int i = r/127, jj = r - i*127; row_ij = i*NN + jj + (jj>=i ? 1:0); }
    else          { row_ij = (r - 16256)*(NN+1); }
    float v = h0[row_ij*ERNN + d];
    unsigned short hi = f2b(v);
    hHi[idx] = hi;
    hLo[idx] = f2b(v - b2f(hi));
    c_all[idx] = c0[row_ij*ERNN + d];
}

// Edge LSTM via bf16x3 MFMA (fp32-accurate). Grid: 128 M-tiles x 8 N-tiles.
// gates = X @ wT^T with X,W each split hi+lo; acc = Xh*Wh + Xl*Wh + Xh*Wl.
__global__ __launch_bounds__(256) void k_edge_gemm(
    const float* __restrict__ edges_t,
    const unsigned short* __restrict__ hHi_in, const unsigned short* __restrict__ hLo_in,
    unsigned short* __restrict__ hHi_out, unsigned short* __restrict__ hLo_out,
    float* __restrict__ h_f32, float* __restrict__ c_all,
    const float* __restrict__ s_enc_w, const float* __restrict__ s_enc_b,
    const unsigned short* __restrict__ s_wHi, const unsigned short* __restrict__ s_wLo,
    const float* __restrict__ s_bs,
    const float* __restrict__ t_enc_w, const float* __restrict__ t_enc_b,
    const unsigned short* __restrict__ t_wHi, const unsigned short* __restrict__ t_wLo,
    const float* __restrict__ t_bs)
{
    __shared__ unsigned short Ah[128*64];
    __shared__ unsigned short Al[128*64];
    __shared__ unsigned short Bh[128*64];
    __shared__ unsigned short Bl[128*64];
    const int tid = threadIdx.x, lane = tid & 63, wid = tid >> 6;
    const int bm = blockIdx.x >> 3, nt = blockIdx.x & 7;
    const bool sp = (bm < 127);
    const int rbase = bm * 128;
    const float* enc_w = sp ? s_enc_w : t_enc_w;
    const float* enc_b = sp ? s_enc_b : t_enc_b;
    const unsigned short* wHi = sp ? s_wHi : t_wHi;
    const unsigned short* wLo = sp ? s_wLo : t_wLo;
    const float* bs = sp ? s_bs : t_bs;
    const int wr = wid >> 1, wc = wid & 1;

    // ks=0 A-tile: encoder, computed + split into LDS
    #pragma unroll
    for (int rep = 0; rep < 4; ++rep) {
        int slot = rep*256 + tid;
        int row = slot >> 3, chunk = slot & 7;
        int r = rbase + row;
        int row_ij;
        if (sp) { int i = r/127, jj = r - i*127; row_ij = i*NN + jj + (jj>=i ? 1:0); }
        else    { row_ij = (r - 16256)*(NN+1); }
        float e0 = edges_t[row_ij*2], e1 = edges_t[row_ij*2+1];
        bf16x8 ph, pl;
        #pragma unroll
        for (int q = 0; q < 8; ++q) {
            int m = chunk*8 + q;
            float v = fmaxf(fmaf(enc_w[m*2], e0, fmaf(enc_w[m*2+1], e1, enc_b[m])), 0.f);
            unsigned short hi = f2b(v);
            ph[q] = (short)hi;
            pl[q] = (short)f2b(v - b2f(hi));
        }
        *(bf16x8*)&Ah[slot*8] = ph;
        *(bf16x8*)&Al[slot*8] = pl;
    }
    // ks=0 B-tiles  [FIX: weight column base is nt*128 + col — was missing nt offset]
    #pragma unroll
    for (int i2 = 0; i2 < 4; ++i2) {
        int slot = (wid*4 + i2)*64 + lane;
        int col = slot >> 3, chunk = slot & 7;
        size_t wb = (size_t)(nt*128 + col)*320 + chunk*8;
        glds16(wHi + wb, (char*)Bh + (wid*4 + i2)*1024);
        glds16(wLo + wb, (char*)Bl + (wid*4 + i2)*1024);
    }

    f32x4 acc[4][4];
    #pragma unroll
    for (int m = 0; m < 4; ++m)
        #pragma unroll
        for (int g = 0; g < 4; ++g)
            acc[m][g] = (f32x4){0.f,0.f,0.f,0.f};

    const int arow = wr*64 + (lane & 15);
    const int bcol = wc*64 + (lane & 15);
    for (int ks = 0; ; ++ks) {
        __syncthreads();   // drains lgkm (enc ds_write) + vmcnt (glds)
        #pragma unroll
        for (int kk = 0; kk < 2; ++kk) {
            int koff = kk*32 + (lane >> 4)*8;
            bf16x8 ah[4], bh[4];
            #pragma unroll
            for (int m = 0; m < 4; ++m) ah[m] = *(const bf16x8*)&Ah[(arow + m*16)*64 + koff];
            #pragma unroll
            for (int g = 0; g < 4; ++g) bh[g] = *(const bf16x8*)&Bh[(bcol + g*16)*64 + koff];
            #pragma unroll
            for (int m = 0; m < 4; ++m)
                #pragma unroll
                for (int g = 0; g < 4; ++g)
                    acc[m][g] = __builtin_amdgcn_mfma_f32_16x16x32_bf16(ah[m], bh[g], acc[m][g], 0, 0, 0);
            bf16x8 al[4];
            #pragma unroll
            for (int m = 0; m < 4; ++m) al[m] = *(const bf16x8*)&Al[(arow + m*16)*64 + koff];
            #pragma unroll
            for (int m = 0; m < 4; ++m)
                #pragma unroll
                for (int g = 0; g < 4; ++g)
                    acc[m][g] = __builtin_amdgcn_mfma_f32_16x16x32_bf16(al[m], bh[g], acc[m][g], 0, 0, 0);
            bf16x8 bl[4];
            #pragma unroll
            for (int g = 0; g < 4; ++g) bl[g] = *(const bf16x8*)&Bl[(bcol + g*16)*64 + koff];
            #pragma unroll
            for (int m = 0; m < 4; ++m)
                #pragma unroll
                for (int g = 0; g < 4; ++g)
                    acc[m][g] = __builtin_amdgcn_mfma_f32_16x16x32_bf16(ah[m], bl[g], acc[m][g], 0, 0, 0);
        }
        if (ks == 4) break;
        __syncthreads();
        #pragma unroll
        for (int i2 = 0; i2 < 4; ++i2) {
            int slot = (wid*4 + i2)*64 + lane;
            int row = slot >> 3, chunk = slot & 7;
            size_t hoff = (size_t)(rbase + row)*256 + ks*64 + chunk*8;
            glds16(hHi_in + hoff, (char*)Ah + (wid*4 + i2)*1024);
            glds16(hLo_in + hoff, (char*)Al + (wid*4 + i2)*1024);
            // [FIX: nt*128 offset on weight columns]
            size_t woff = (size_t)(nt*128 + row)*320 + (ks+1)*64 + chunk*8;
            glds16(wHi + woff, (char*)Bh + (wid*4 + i2)*1024);
            glds16(wLo + woff, (char*)Bl + (wid*4 + i2)*1024);
        }
    }

    // epilogue: lane-local gates (n-fragment index == gate)
    const int chl = lane & 15, q4 = (lane >> 4)*4;
    const int ch = (nt*2 + wc)*16 + chl;           // channel in [0,256)
    const int cbase = nt*128 + wc*64 + chl;        // permuted col of gate i
    const float b0 = bs[cbase], b1 = bs[cbase+16], b2 = bs[cbase+32], b3 = bs[cbase+48];
    #pragma unroll
    for (int m = 0; m < 4; ++m) {
        #pragma unroll
        for (int rg = 0; rg < 4; ++rg) {
            int row = rbase + wr*64 + m*16 + q4 + rg;
            float gi = acc[m][0][rg] + b0;
            float gf = acc[m][1][rg] + b1;
            float gg = acc[m][2][rg] + b2;
            float go = acc[m][3][rg] + b3;
            size_t off = (size_t)row*256 + ch;
            float c_old = c_all[off];
            float c2 = sigm(gf)*c_old + sigm(gi)*tanhf(gg);
            float h2 = sigm(go)*tanhf(c2);
            c_all[off] = c2;
            unsigned short hi = f2b(h2);
            hHi_out[off] = hi;
            hLo_out[off] = f2b(h2 - b2f(hi));
            h_f32[off] = h2;
        }
    }
}

// Per-node: attention (folded) + node LSTM + output. h_f32 in se-order.
__global__ __launch_bounds__(256) void k_node(
    const float* __restrict__ nodes_t,
    const float* __restrict__ h,                 // [16384,256] fp32, se-order
    float* __restrict__ h_n, float* __restrict__ c_n,
    float* __restrict__ out_t,
    const float* __restrict__ att_t_w, const float* __restrict__ att_t_b,
    const float* __restrict__ att_s_w, const float* __restrict__ att_s_b,
    const float* __restrict__ n_enc_w, const float* __restrict__ n_enc_b,
    const float* __restrict__ n_attn_w, const float* __restrict__ n_attn_b,
    const float* __restrict__ n_wT, const float* __restrict__ n_bsum,
    const float* __restrict__ out_w, const float* __restrict__ out_b)
{
    const int i = blockIdx.x, tid = threadIdx.x;
    __shared__ float ht[ERNN];
    __shared__ float te[64];
    __shared__ float u[ERNN];
    __shared__ float lg[128];
    __shared__ float cat[512];
    __shared__ float xc[128];
    __shared__ float hnl[128];
    __shared__ float gl[512];
    __shared__ float smax, ssum, c0s;

    ht[tid] = h[(size_t)(16256 + i)*256 + tid];
    __syncthreads();
    if (tid < 64) {
        float s = att_t_b[tid];
        const float* wr = att_t_w + tid*ERNN;
        for (int k = 0; k < ERNN; ++k) s = fmaf(wr[k], ht[k], s);
        te[tid] = s;
    }
    __syncthreads();
    {
        float s = 0.f;
        for (int m = 0; m < 64; ++m) s = fmaf(att_s_w[m*ERNN + tid], te[m], s);
        u[tid] = s;
    }
    if (tid == 0) {
        float s = 0.f;
        for (int m = 0; m < 64; ++m) s = fmaf(te[m], att_s_b[m], s);
        c0s = s;
    }
    __syncthreads();
    {
        int slot = tid >> 1, half = tid & 1;
        float part = 0.f;
        if (slot < 127) {
            const float* hs = h + (size_t)(i*127 + slot)*256 + half*128;
            const float* uu = u + half*128;
            for (int d = 0; d < 128; ++d) part = fmaf(uu[d], hs[d], part);
        }
        part += __shfl_xor(part, 1);
        if (slot < 127 && (half == 0)) lg[slot] = (part + c0s) * TEMPSC;
        if (tid == 255) lg[127] = -1e30f;
    }
    __syncthreads();
    if (tid < 64) {
        float a = fmaxf(lg[tid], lg[tid+64]);
        for (int off = 32; off; off >>= 1) a = fmaxf(a, __shfl_xor(a, off));
        if (tid == 0) smax = a;
    }
    __syncthreads();
    if (tid < 128) lg[tid] = (tid < 127) ? __expf(lg[tid] - smax) : 0.f;
    __syncthreads();
    if (tid < 64) {
        float a = lg[tid] + lg[tid+64];
        for (int off = 32; off; off >>= 1) a += __shfl_xor(a, off);
        if (tid == 0) ssum = a;
    }
    __syncthreads();
    {
        float acc = 0.f;
        for (int slot = 0; slot < 127; ++slot)
            acc = fmaf(lg[slot], h[(size_t)(i*127 + slot)*256 + tid], acc);
        cat[tid] = ht[tid];
        cat[256 + tid] = acc / ssum;
    }
    if (tid < 128) hnl[tid] = h_n[i*128 + tid];
    __syncthreads();
    if (tid < 64) {
        float p0 = nodes_t[i*2], p1 = nodes_t[i*2+1];
        xc[tid] = fmaxf(fmaf(n_enc_w[tid*2], p0, fmaf(n_enc_w[tid*2+1], p1, n_enc_b[tid])), 0.f);
    } else if (tid < 128) {
        int m = tid - 64;
        float s = n_attn_b[m];
        const float* wr = n_attn_w + m*512;
        for (int d = 0; d < 512; ++d) s = fmaf(wr[d], cat[d], s);
        xc[tid] = fmaxf(s, 0.f);
    }
    __syncthreads();
    #pragma unroll
    for (int rep = 0; rep < 2; ++rep) {
        int n = tid + rep*256;
        float s = n_bsum[n];
        for (int k = 0; k < 128; ++k) s = fmaf(n_wT[k*512 + n], xc[k], s);
        for (int k = 0; k < 128; ++k) s = fmaf(n_wT[(128+k)*512 + n], hnl[k], s);
        gl[n] = s;
    }
    __syncthreads();
    if (tid < 128) {
        float co = c_n[i*128 + tid];
        float c2 = sigm(gl[128+tid])*co + sigm(gl[tid])*tanhf(gl[256+tid]);
        float h2 = sigm(gl[384+tid])*tanhf(c2);
        c_n[i*128+tid] = c2;
        h_n[i*128+tid] = h2;
        hnl[tid] = h2;
    }
    __syncthreads();
    if (tid < 5) {
        float s = out_b[tid];
        const float* wr = out_w + tid*128;
        for (int k = 0; k < 128; ++k) s = fmaf(wr[k], hnl[k], s);
        out_t[i*5 + tid] = s;
    }
}

extern "C" void kernel_launch(void* const* d_in, const int* in_sizes, int n_in,
                              void* d_out, int out_size, void* d_ws, size_t ws_size,
                              hipStream_t stream)
{
    const float* nodes   = (const float*)d_in[0];
    const float* edges   = (const float*)d_in[1];
    const float* h_e0    = (const float*)d_in[2];
    const float* c_e0    = (const float*)d_in[3];
    const float* h_n0    = (const float*)d_in[4];
    const float* c_n0    = (const float*)d_in[5];
    const float* t_enc_w = (const float*)d_in[6];
    const float* t_enc_b = (const float*)d_in[7];
    const float* t_wih   = (const float*)d_in[8];
    const float* t_whh   = (const float*)d_in[9];
    const float* t_bih   = (const float*)d_in[10];
    const float* t_bhh   = (const float*)d_in[11];
    const float* s_enc_w = (const float*)d_in[12];
    const float* s_enc_b = (const float*)d_in[13];
    const float* s_wih   = (const float*)d_in[14];
    const float* s_whh   = (const float*)d_in[15];
    const float* s_bih   = (const float*)d_in[16];
    const float* s_bhh   = (const float*)d_in[17];
    const float* att_t_w = (const float*)d_in[18];
    const float* att_t_b = (const float*)d_in[19];
    const float* att_s_w = (const float*)d_in[20];
    const float* att_s_b = (const float*)d_in[21];
    const float* n_enc_w = (const float*)d_in[22];
    const float* n_enc_b = (const float*)d_in[23];
    const float* n_attn_w= (const float*)d_in[24];
    const float* n_attn_b= (const float*)d_in[25];
    const float* n_wih   = (const float*)d_in[26];
    const float* n_whh   = (const float*)d_in[27];
    const float* n_bih   = (const float*)d_in[28];
    const float* n_bhh   = (const float*)d_in[29];
    const float* out_w   = (const float*)d_in[30];
    const float* out_b   = (const float*)d_in[31];
    float* out = (float*)d_out;

    char* p = (char*)d_ws;
    float* c_all = (float*)p;            p += (size_t)16384*256*4;
    float* h_f32 = (float*)p;            p += (size_t)16384*256*4;
    float* h_nn  = (float*)p;            p += 128*128*4;
    float* c_nn  = (float*)p;            p += 128*128*4;
    float* s_bs  = (float*)p;            p += 1024*4;
    float* t_bs  = (float*)p;            p += 1024*4;
    float* n_wT  = (float*)p;            p += 256*512*4;
    float* n_bs  = (float*)p;            p += 512*4;
    unsigned short* hHi_a = (unsigned short*)p; p += (size_t)16384*256*2;
    unsigned short* hLo_a = (unsigned short*)p; p += (size_t)16384*256*2;
    unsigned short* hHi_b = (unsigned short*)p; p += (size_t)16384*256*2;
    unsigned short* hLo_b = (unsigned short*)p; p += (size_t)16384*256*2;
    unsigned short* s_wHi = (unsigned short*)p; p += 1024*320*2;
    unsigned short* s_wLo = (unsigned short*)p; p += 1024*320*2;
    unsigned short* t_wHi = (unsigned short*)p; p += 1024*320*2;
    unsigned short* t_wLo = (unsigned short*)p; p += 1024*320*2;

    hipMemcpyAsync(h_nn, h_n0, 128*128*sizeof(float), hipMemcpyDeviceToDevice, stream);
    hipMemcpyAsync(c_nn, c_n0, 128*128*sizeof(float), hipMemcpyDeviceToDevice, stream);

    k_init_state<<<16384, 256, 0, stream>>>(h_e0, c_e0, hHi_a, hLo_a, c_all);
    k_prep_w<<<1280, 256, 0, stream>>>(s_wih, s_whh, s_wHi, s_wLo);
    k_prep_w<<<1280, 256, 0, stream>>>(t_wih, t_whh, t_wHi, t_wLo);
    k_prep_b<<<4, 256, 0, stream>>>(s_bih, s_bhh, s_bs);
    k_prep_b<<<4, 256, 0, stream>>>(t_bih, t_bhh, t_bs);
    k_transpose<<<(512*128+255)/256, 256, 0, stream>>>(n_wih, n_wT, 512, 128);
    k_transpose<<<(512*128+255)/256, 256, 0, stream>>>(n_whh, n_wT + 128*512, 512, 128);
    k_bias_sum<<<2, 256, 0, stream>>>(n_bih, n_bhh, n_bs, 512);

    for (int t = 0; t < TT; ++t) {
        const unsigned short* hHi_in = (t & 1) ? hHi_b : hHi_a;
        const unsigned short* hLo_in = (t & 1) ? hLo_b : hLo_a;
        unsigned short* hHi_out = (t & 1) ? hHi_a : hHi_b;
        unsigned short* hLo_out = (t & 1) ? hLo_a : hLo_b;
        k_edge_gemm<<<1024, 256, 0, stream>>>(edges + (size_t)t*16384*2,
            hHi_in, hLo_in, hHi_out, hLo_out, h_f32, c_all,
            s_enc_w, s_enc_b, s_wHi, s_wLo, s_bs,
            t_enc_w, t_enc_b, t_wHi, t_wLo, t_bs);
        k_node<<<NN, 256, 0, stream>>>(nodes + (size_t)t*NN*2, h_f32, h_nn, c_nn,
            out + (size_t)t*NN*5,
            att_t_w, att_t_b, att_s_w, att_s_b, n_enc_w, n_enc_b,
            n_attn_w, n_attn_b, n_wT, n_bs, out_w, out_b);
    }
}

// Round 5
// 1920.138 us; speedup vs baseline: 2.1470x; 1.0208x over previous
//
#include <hip/hip_runtime.h>
#include <cmath>

#define NN 128
#define TT 20
#define ERNN 256
#define TEMPSC 15.875f /* (N-1)/sqrt(ATT) = 127/8 */

typedef __attribute__((ext_vector_type(8))) short bf16x8;
typedef __attribute__((ext_vector_type(4))) float f32x4;

__device__ __forceinline__ float sigm(float x){ return 1.f/(1.f+__expf(-x)); }
__device__ __forceinline__ float b2f(unsigned short u){ union{unsigned int i; float f;} v; v.i = ((unsigned int)u)<<16; return v.f; }
__device__ __forceinline__ unsigned short f2b(float x){ union{float f; unsigned int u;} v; v.f = x; unsigned int r = v.u + 0x7fffu + ((v.u>>16)&1u); return (unsigned short)(r>>16); }

typedef __attribute__((address_space(3))) unsigned int lds_u32;
typedef __attribute__((address_space(1))) unsigned int glb_u32;
__device__ __forceinline__ void glds16(const void* g, void* l){
    __builtin_amdgcn_global_load_lds((const glb_u32*)g, (lds_u32*)l, 16, 0, 0);
}

__global__ void k_transpose(const float* __restrict__ s, float* __restrict__ d, int R, int C){
    int i = blockIdx.x*256 + threadIdx.x;
    if (i < R*C){ int r = i / C, c = i - r*C; d[c*R + r] = s[i]; }
}

__global__ void k_bias_sum(const float* __restrict__ a, const float* __restrict__ b,
                           float* __restrict__ o, int n){
    int i = blockIdx.x*256 + threadIdx.x;
    if (i < n) o[i] = a[i] + b[i];
}

// wT[c][k] split hi/lo bf16; c gate-interleaved: ch=(c>>6)*16+(c&15), g=(c>>4)&3
__global__ void k_prep_w(const float* __restrict__ wih, const float* __restrict__ whh,
                         unsigned short* __restrict__ wHi, unsigned short* __restrict__ wLo){
    int idx = blockIdx.x*256 + threadIdx.x;
    if (idx >= 1024*320) return;
    int c = idx / 320, k = idx - c*320;
    int ch = ((c>>6)<<4) + (c&15), g = (c>>4)&3;
    int r = g*256 + ch;
    float v = (k < 64) ? wih[r*64 + k] : whh[r*256 + (k-64)];
    unsigned short hi = f2b(v);
    wHi[idx] = hi;
    wLo[idx] = f2b(v - b2f(hi));
}

__global__ void k_prep_b(const float* __restrict__ bih, const float* __restrict__ bhh,
                         float* __restrict__ bs){
    int c = blockIdx.x*256 + threadIdx.x;
    if (c < 1024){ int ch = ((c>>6)<<4)+(c&15), g=(c>>4)&3; int r = g*256+ch; bs[c] = bih[r] + bhh[r]; }
}

// gather (i,j)-layout initial state into se-order (h as bf16)
__global__ void k_init_state(const float* __restrict__ h0, const float* __restrict__ c0,
                             unsigned short* __restrict__ hHi, float* __restrict__ c_all){
    int idx = blockIdx.x*256 + threadIdx.x;
    if (idx >= 16384*256) return;
    int r = idx >> 8, d = idx & 255;
    int row_ij;
    if (r < 16256){ int i = r/127, jj = r - i*127; row_ij = i*NN + jj + (jj>=i ? 1:0); }
    else          { row_ij = (r - 16256)*(NN+1); }
    hHi[idx] = f2b(h0[row_ij*ERNN + d]);
    c_all[idx] = c0[row_ij*ERNN + d];
}

// Edge LSTM via 2-product MFMA (A bf16, W split hi+lo): gates = Ah*Wh + Ah*Wl.
// LDS tiles in 16B-chunk layout: chunk c=(kc*128+row) at byte offset c*16 — fragment
// ds_read_b128 lands 16 lanes on consecutive chunks (2-way bank alias = free).
// Staging keeps glds-linear dest; global SOURCE addresses carry the permutation (m173).
__global__ __launch_bounds__(256) void k_edge_gemm(
    const float* __restrict__ edges_t,
    const unsigned short* __restrict__ h_in, unsigned short* __restrict__ h_out,
    float* __restrict__ h_f32, float* __restrict__ c_all,
    const float* __restrict__ s_enc_w, const float* __restrict__ s_enc_b,
    const unsigned short* __restrict__ s_wHi, const unsigned short* __restrict__ s_wLo,
    const float* __restrict__ s_bs,
    const float* __restrict__ t_enc_w, const float* __restrict__ t_enc_b,
    const unsigned short* __restrict__ t_wHi, const unsigned short* __restrict__ t_wLo,
    const float* __restrict__ t_bs)
{
    __shared__ unsigned short Ah[128*64];
    __shared__ unsigned short Bh[128*64];
    __shared__ unsigned short Bl[128*64];
    const int tid = threadIdx.x, lane = tid & 63, wid = tid >> 6;
    // XCD-chunked swizzle (bijective: 1024 = 8 XCD * 128): all 8 nt of a bm + 16
    // consecutive bm land on one XCD's L2 (~2.3 MB working set < 4 MB).
    const int wg = (blockIdx.x & 7)*128 + (blockIdx.x >> 3);
    const int bm = wg >> 3, nt = wg & 7;
    const bool sp = (bm < 127);
    const int rbase = bm * 128;
    const float* enc_w = sp ? s_enc_w : t_enc_w;
    const float* enc_b = sp ? s_enc_b : t_enc_b;
    const unsigned short* wHi = sp ? s_wHi : t_wHi;
    const unsigned short* wLo = sp ? s_wLo : t_wLo;
    const float* bs = sp ? s_bs : t_bs;
    const int wr = wid >> 1, wc = wid & 1;

    // ks=0 A-tile: encoder, computed into LDS in chunk layout
    #pragma unroll
    for (int rep = 0; rep < 4; ++rep) {
        int c = rep*256 + tid;
        int row = c & 127, kc = c >> 7;
        int r = rbase + row;
        int row_ij;
        if (sp) { int i = r/127, jj = r - i*127; row_ij = i*NN + jj + (jj>=i ? 1:0); }
        else    { row_ij = (r - 16256)*(NN+1); }
        float e0 = edges_t[row_ij*2], e1 = edges_t[row_ij*2+1];
        bf16x8 ph;
        #pragma unroll
        for (int q = 0; q < 8; ++q) {
            int m = kc*8 + q;
            float v = fmaxf(fmaf(enc_w[m*2], e0, fmaf(enc_w[m*2+1], e1, enc_b[m])), 0.f);
            ph[q] = (short)f2b(v);
        }
        *(bf16x8*)&Ah[c*8] = ph;
    }
    // ks=0 B-tiles (chunk layout source)
    #pragma unroll
    for (int i2 = 0; i2 < 4; ++i2) {
        int c = (wid*4 + i2)*64 + lane;
        int col = c & 127, kc = c >> 7;
        size_t wb = (size_t)(nt*128 + col)*320 + kc*8;
        glds16(wHi + wb, (char*)Bh + (wid*4 + i2)*1024);
        glds16(wLo + wb, (char*)Bl + (wid*4 + i2)*1024);
    }

    f32x4 acc[4][4];
    #pragma unroll
    for (int m = 0; m < 4; ++m)
        #pragma unroll
        for (int g = 0; g < 4; ++g)
            acc[m][g] = (f32x4){0.f,0.f,0.f,0.f};

    const int arow = wr*64 + (lane & 15);
    const int bcol = wc*64 + (lane & 15);
    const int kg = lane >> 4;      // 0..3
    for (int ks = 0; ; ++ks) {
        __syncthreads();   // drains lgkm (enc ds_write) + vmcnt (glds)
        #pragma unroll
        for (int kk = 0; kk < 2; ++kk) {
            int kc = kk*4 + kg;
            bf16x8 a[4], bh[4];
            #pragma unroll
            for (int m = 0; m < 4; ++m) a[m] = *(const bf16x8*)&Ah[(kc*128 + arow + m*16)*8];
            #pragma unroll
            for (int g = 0; g < 4; ++g) bh[g] = *(const bf16x8*)&Bh[(kc*128 + bcol + g*16)*8];
            #pragma unroll
            for (int m = 0; m < 4; ++m)
                #pragma unroll
                for (int g = 0; g < 4; ++g)
                    acc[m][g] = __builtin_amdgcn_mfma_f32_16x16x32_bf16(a[m], bh[g], acc[m][g], 0, 0, 0);
            bf16x8 bl[4];
            #pragma unroll
            for (int g = 0; g < 4; ++g) bl[g] = *(const bf16x8*)&Bl[(kc*128 + bcol + g*16)*8];
            #pragma unroll
            for (int m = 0; m < 4; ++m)
                #pragma unroll
                for (int g = 0; g < 4; ++g)
                    acc[m][g] = __builtin_amdgcn_mfma_f32_16x16x32_bf16(a[m], bl[g], acc[m][g], 0, 0, 0);
        }
        if (ks == 4) break;
        __syncthreads();
        #pragma unroll
        for (int i2 = 0; i2 < 4; ++i2) {
            int c = (wid*4 + i2)*64 + lane;
            int row = c & 127, kc = c >> 7;
            glds16(h_in + (size_t)(rbase + row)*256 + ks*64 + kc*8,
                   (char*)Ah + (wid*4 + i2)*1024);
            size_t wb = (size_t)(nt*128 + row)*320 + (ks+1)*64 + kc*8;
            glds16(wHi + wb, (char*)Bh + (wid*4 + i2)*1024);
            glds16(wLo + wb, (char*)Bl + (wid*4 + i2)*1024);
        }
    }

    // epilogue: lane-local gates (n-fragment index == gate)
    const int chl = lane & 15, q4 = (lane >> 4)*4;
    const int ch = (nt*2 + wc)*16 + chl;           // channel in [0,256)
    const int cbase = nt*128 + wc*64 + chl;        // permuted col of gate i
    const float b0 = bs[cbase], b1 = bs[cbase+16], b2 = bs[cbase+32], b3 = bs[cbase+48];
    #pragma unroll
    for (int m = 0; m < 4; ++m) {
        #pragma unroll
        for (int rg = 0; rg < 4; ++rg) {
            int row = rbase + wr*64 + m*16 + q4 + rg;
            float gi = acc[m][0][rg] + b0;
            float gf = acc[m][1][rg] + b1;
            float gg = acc[m][2][rg] + b2;
            float go = acc[m][3][rg] + b3;
            size_t off = (size_t)row*256 + ch;
            float c_old = c_all[off];
            float c2 = sigm(gf)*c_old + sigm(gi)*tanhf(gg);
            float h2 = sigm(go)*tanhf(c2);
            c_all[off] = c2;
            h_out[off] = f2b(h2);
            h_f32[off] = h2;
        }
    }
}

// Per-node: attention (folded) + node LSTM + output. h_f32 in se-order.
__global__ __launch_bounds__(256) void k_node(
    const float* __restrict__ nodes_t,
    const float* __restrict__ h,                 // [16384,256] fp32, se-order
    float* __restrict__ h_n, float* __restrict__ c_n,
    float* __restrict__ out_t,
    const float* __restrict__ att_t_w, const float* __restrict__ att_t_b,
    const float* __restrict__ att_s_w, const float* __restrict__ att_s_b,
    const float* __restrict__ n_enc_w, const float* __restrict__ n_enc_b,
    const float* __restrict__ n_attn_w, const float* __restrict__ n_attn_b,
    const float* __restrict__ n_wT, const float* __restrict__ n_bsum,
    const float* __restrict__ out_w, const float* __restrict__ out_b)
{
    const int i = blockIdx.x, tid = threadIdx.x;
    __shared__ float ht[ERNN];
    __shared__ float te[64];
    __shared__ float u[ERNN];
    __shared__ float lg[128];
    __shared__ float cat[512];
    __shared__ float xc[128];
    __shared__ float hnl[128];
    __shared__ float gl[512];
    __shared__ float smax, ssum, c0s;

    ht[tid] = h[(size_t)(16256 + i)*256 + tid];
    __syncthreads();
    if (tid < 64) {
        float s = att_t_b[tid];
        const float* wr = att_t_w + tid*ERNN;
        for (int k = 0; k < ERNN; ++k) s = fmaf(wr[k], ht[k], s);
        te[tid] = s;
    }
    __syncthreads();
    {
        float s = 0.f;
        for (int m = 0; m < 64; ++m) s = fmaf(att_s_w[m*ERNN + tid], te[m], s);
        u[tid] = s;
    }
    if (tid == 0) {
        float s = 0.f;
        for (int m = 0; m < 64; ++m) s = fmaf(te[m], att_s_b[m], s);
        c0s = s;
    }
    __syncthreads();
    {
        int slot = tid >> 1, half = tid & 1;
        float part = 0.f;
        if (slot < 127) {
            const float* hs = h + (size_t)(i*127 + slot)*256 + half*128;
            const float* uu = u + half*128;
            for (int d = 0; d < 128; ++d) part = fmaf(uu[d], hs[d], part);
        }
        part += __shfl_xor(part, 1);
        if (slot < 127 && (half == 0)) lg[slot] = (part + c0s) * TEMPSC;
        if (tid == 255) lg[127] = -1e30f;
    }
    __syncthreads();
    if (tid < 64) {
        float a = fmaxf(lg[tid], lg[tid+64]);
        for (int off = 32; off; off >>= 1) a = fmaxf(a, __shfl_xor(a, off));
        if (tid == 0) smax = a;
    }
    __syncthreads();
    if (tid < 128) lg[tid] = (tid < 127) ? __expf(lg[tid] - smax) : 0.f;
    __syncthreads();
    if (tid < 64) {
        float a = lg[tid] + lg[tid+64];
        for (int off = 32; off; off >>= 1) a += __shfl_xor(a, off);
        if (tid == 0) ssum = a;
    }
    __syncthreads();
    {
        float acc = 0.f;
        for (int slot = 0; slot < 127; ++slot)
            acc = fmaf(lg[slot], h[(size_t)(i*127 + slot)*256 + tid], acc);
        cat[tid] = ht[tid];
        cat[256 + tid] = acc / ssum;
    }
    if (tid < 128) hnl[tid] = h_n[i*128 + tid];
    __syncthreads();
    if (tid < 64) {
        float p0 = nodes_t[i*2], p1 = nodes_t[i*2+1];
        xc[tid] = fmaxf(fmaf(n_enc_w[tid*2], p0, fmaf(n_enc_w[tid*2+1], p1, n_enc_b[tid])), 0.f);
    } else if (tid < 128) {
        int m = tid - 64;
        float s = n_attn_b[m];
        const float* wr = n_attn_w + m*512;
        for (int d = 0; d < 512; ++d) s = fmaf(wr[d], cat[d], s);
        xc[tid] = fmaxf(s, 0.f);
    }
    __syncthreads();
    #pragma unroll
    for (int rep = 0; rep < 2; ++rep) {
        int n = tid + rep*256;
        float s = n_bsum[n];
        for (int k = 0; k < 128; ++k) s = fmaf(n_wT[k*512 + n], xc[k], s);
        for (int k = 0; k < 128; ++k) s = fmaf(n_wT[(128+k)*512 + n], hnl[k], s);
        gl[n] = s;
    }
    __syncthreads();
    if (tid < 128) {
        float co = c_n[i*128 + tid];
        float c2 = sigm(gl[128+tid])*co + sigm(gl[tid])*tanhf(gl[256+tid]);
        float h2 = sigm(gl[384+tid])*tanhf(c2);
        c_n[i*128+tid] = c2;
        h_n[i*128+tid] = h2;
        hnl[tid] = h2;
    }
    __syncthreads();
    if (tid < 5) {
        float s = out_b[tid];
        const float* wr = out_w + tid*128;
        for (int k = 0; k < 128; ++k) s = fmaf(wr[k], hnl[k], s);
        out_t[i*5 + tid] = s;
    }
}

extern "C" void kernel_launch(void* const* d_in, const int* in_sizes, int n_in,
                              void* d_out, int out_size, void* d_ws, size_t ws_size,
                              hipStream_t stream)
{
    const float* nodes   = (const float*)d_in[0];
    const float* edges   = (const float*)d_in[1];
    const float* h_e0    = (const float*)d_in[2];
    const float* c_e0    = (const float*)d_in[3];
    const float* h_n0    = (const float*)d_in[4];
    const float* c_n0    = (const float*)d_in[5];
    const float* t_enc_w = (const float*)d_in[6];
    const float* t_enc_b = (const float*)d_in[7];
    const float* t_wih   = (const float*)d_in[8];
    const float* t_whh   = (const float*)d_in[9];
    const float* t_bih   = (const float*)d_in[10];
    const float* t_bhh   = (const float*)d_in[11];
    const float* s_enc_w = (const float*)d_in[12];
    const float* s_enc_b = (const float*)d_in[13];
    const float* s_wih   = (const float*)d_in[14];
    const float* s_whh   = (const float*)d_in[15];
    const float* s_bih   = (const float*)d_in[16];
    const float* s_bhh   = (const float*)d_in[17];
    const float* att_t_w = (const float*)d_in[18];
    const float* att_t_b = (const float*)d_in[19];
    const float* att_s_w = (const float*)d_in[20];
    const float* att_s_b = (const float*)d_in[21];
    const float* n_enc_w = (const float*)d_in[22];
    const float* n_enc_b = (const float*)d_in[23];
    const float* n_attn_w= (const float*)d_in[24];
    const float* n_attn_b= (const float*)d_in[25];
    const float* n_wih   = (const float*)d_in[26];
    const float* n_whh   = (const float*)d_in[27];
    const float* n_bih   = (const float*)d_in[28];
    const float* n_bhh   = (const float*)d_in[29];
    const float* out_w   = (const float*)d_in[30];
    const float* out_b   = (const float*)d_in[31];
    float* out = (float*)d_out;

    char* p = (char*)d_ws;
    float* c_all = (float*)p;            p += (size_t)16384*256*4;
    float* h_f32 = (float*)p;            p += (size_t)16384*256*4;
    float* h_nn  = (float*)p;            p += 128*128*4;
    float* c_nn  = (float*)p;            p += 128*128*4;
    float* s_bs  = (float*)p;            p += 1024*4;
    float* t_bs  = (float*)p;            p += 1024*4;
    float* n_wT  = (float*)p;            p += 256*512*4;
    float* n_bs  = (float*)p;            p += 512*4;
    unsigned short* hHi_a = (unsigned short*)p; p += (size_t)16384*256*2;
    unsigned short* hHi_b = (unsigned short*)p; p += (size_t)16384*256*2;
    unsigned short* s_wHi = (unsigned short*)p; p += 1024*320*2;
    unsigned short* s_wLo = (unsigned short*)p; p += 1024*320*2;
    unsigned short* t_wHi = (unsigned short*)p; p += 1024*320*2;
    unsigned short* t_wLo = (unsigned short*)p; p += 1024*320*2;

    hipMemcpyAsync(h_nn, h_n0, 128*128*sizeof(float), hipMemcpyDeviceToDevice, stream);
    hipMemcpyAsync(c_nn, c_n0, 128*128*sizeof(float), hipMemcpyDeviceToDevice, stream);

    k_init_state<<<16384, 256, 0, stream>>>(h_e0, c_e0, hHi_a, c_all);
    k_prep_w<<<1280, 256, 0, stream>>>(s_wih, s_whh, s_wHi, s_wLo);
    k_prep_w<<<1280, 256, 0, stream>>>(t_wih, t_whh, t_wHi, t_wLo);
    k_prep_b<<<4, 256, 0, stream>>>(s_bih, s_bhh, s_bs);
    k_prep_b<<<4, 256, 0, stream>>>(t_bih, t_bhh, t_bs);
    k_transpose<<<(512*128+255)/256, 256, 0, stream>>>(n_wih, n_wT, 512, 128);
    k_transpose<<<(512*128+255)/256, 256, 0, stream>>>(n_whh, n_wT + 128*512, 512, 128);
    k_bias_sum<<<2, 256, 0, stream>>>(n_bih, n_bhh, n_bs, 512);

    for (int t = 0; t < TT; ++t) {
        const unsigned short* h_in = (t & 1) ? hHi_b : hHi_a;
        unsigned short*       h_out= (t & 1) ? hHi_a : hHi_b;
        k_edge_gemm<<<1024, 256, 0, stream>>>(edges + (size_t)t*16384*2,
            h_in, h_out, h_f32, c_all,
            s_enc_w, s_enc_b, s_wHi, s_wLo, s_bs,
            t_enc_w, t_enc_b, t_wHi, t_wLo, t_bs);
        k_node<<<NN, 256, 0, stream>>>(nodes + (size_t)t*NN*2, h_f32, h_nn, c_nn,
            out + (size_t)t*NN*5,
            att_t_w, att_t_b, att_s_w, att_s_b, n_enc_w, n_enc_b,
            n_attn_w, n_attn_b, n_wT, n_bs, out_w, out_b);
    }
}